// Round 18
// baseline (37.288 us; speedup 1.0000x reference)
//
#include <hip/hip_runtime.h>

#define B_ 8
#define C_ 256
#define S_ 2048
#define T_ (B_*S_)      // 16384 tokens

typedef short s8v __attribute__((ext_vector_type(8)));
typedef short s4v __attribute__((ext_vector_type(4)));
typedef float f4v __attribute__((ext_vector_type(4)));

__device__ inline short f2b(float f){            // fp32 -> bf16 RNE
  unsigned u = __builtin_bit_cast(unsigned, f);
  unsigned r = (u + 0x7FFFu + ((u >> 16) & 1u)) >> 16;
  return (short)r;
}
__device__ inline float b2f(short s){
  unsigned u = ((unsigned)(unsigned short)s) << 16;
  return __builtin_bit_cast(float, u);
}

// K1: fused prep, 1216 blocks, no global atomics (R11 proven, byte-identical).
__global__ __launch_bounds__(256) void k_pre(const float* __restrict__ x, short* __restrict__ xT,
                                             const float* __restrict__ wgt, short* __restrict__ wT2,
                                             const int* __restrict__ idx, int* __restrict__ segCnt,
                                             int* __restrict__ segBucket, float* __restrict__ idx_out){
  __shared__ float tile[64][65];
  int tid = threadIdx.x;
  int bid = blockIdx.x;

  if (bid < 1024){
    int b  = bid >> 7;
    int ct = (bid >> 5) & 3;
    int st = bid & 31;
    const float* xb = x + b*(C_*S_);
    #pragma unroll
    for (int it = 0; it < 4; ++it){
      int row = it*16 + (tid >> 4);       // c-local
      int s4  = tid & 15;
      float4 v = *(const float4*)(xb + (ct*64 + row)*S_ + st*64 + s4*4);
      tile[row][s4*4+0] = v.x; tile[row][s4*4+1] = v.y;
      tile[row][s4*4+2] = v.z; tile[row][s4*4+3] = v.w;
    }
    __syncthreads();
    #pragma unroll
    for (int it = 0; it < 4; ++it){
      int srow = it*16 + (tid >> 4);      // s-local
      int c4   = tid & 15;
      s4v o;
      o[0] = f2b(tile[c4*4+0][srow]); o[1] = f2b(tile[c4*4+1][srow]);
      o[2] = f2b(tile[c4*4+2][srow]); o[3] = f2b(tile[c4*4+3][srow]);
      *(s4v*)(xT + (b*S_ + st*64 + srow)*C_ + ct*64 + c4*4) = o;
    }
  } else if (bid < 1152){
    int wb_ = bid - 1024;
    int r  = wb_ >> 4;
    int ct = (wb_ >> 2) & 3;   // c-tile (K dim)
    int mt = wb_ & 3;          // n-tile
    const float* wsrc = wgt + r*(C_*256);
    #pragma unroll
    for (int it = 0; it < 4; ++it){
      int row = it*16 + (tid >> 4);       // c-local
      int m4  = tid & 15;
      float4 v = *(const float4*)(wsrc + (ct*64 + row)*256 + mt*64 + m4*4);
      tile[row][m4*4+0] = v.x; tile[row][m4*4+1] = v.y;
      tile[row][m4*4+2] = v.z; tile[row][m4*4+3] = v.w;
    }
    __syncthreads();
    char* wdst = (char*)wT2 + r*131072;
    #pragma unroll
    for (int it = 0; it < 2; ++it){
      int q  = it*256 + tid;
      int ml = q >> 3;                    // n-local
      int ck = q & 7;                     // 8 consecutive c
      int mg = mt*64 + ml;
      int cg = ct*64 + ck*8;
      int kcb = cg >> 5, klocal = cg & 31;
      s8v o;
      #pragma unroll
      for (int j = 0; j < 8; ++j) o[j] = f2b(tile[ck*8 + j][ml]);
      *(s8v*)(wdst + kcb*16384 + mg*64 + klocal*2) = o;   // linear [kc][n][k32]
    }
  } else {
    int seg = bid - 1152;
    __shared__ int lcount[8];
    __shared__ int lbase[8];
    int t = seg*256 + tid;
    if (tid < 8) lcount[tid] = 0;
    __syncthreads();
    int ei = idx[t];
    int e  = ei & 7;
    int lp = atomicAdd(&lcount[e], 1);    // LDS atomic, block-local
    __syncthreads();
    if (tid == 0){
      int a0 = 0;
      #pragma unroll
      for (int e2 = 0; e2 < 8; ++e2){ lbase[e2] = a0; a0 += lcount[e2]; }
    }
    __syncthreads();
    if (tid < 8) segCnt[seg*8 + tid] = lcount[tid];
    segBucket[seg*256 + lbase[e] + lp] = t;
    idx_out[t] = (float)ei;
  }
}

// K2: grouped GEMM — EXACT R11 body (proven best).
__global__ __launch_bounds__(256,2) void k_gemm(const short* __restrict__ xT, const short* __restrict__ wT2,
                                                const float* __restrict__ bias, const int* __restrict__ segCnt,
                                                const int* __restrict__ segBucket, const int* __restrict__ rate,
                                                short* __restrict__ yT){
  int bid = blockIdx.x;
  int e   = bid & 7;
  int seg = bid >> 3;

  __shared__ short A [32*256];     // 16KB
  __shared__ short OS[32*256];     // 16KB out-stage
  __shared__ float biasS[256];
  __shared__ int   toks[32];

  int tid  = threadIdx.x;
  int lane = tid & 63, wv = tid >> 6;
  int l15  = lane & 15, lq = lane >> 4;

  biasS[tid] = bias[e*256 + tid];
  int rate_e = rate[e];

  int off = 0, cnt = 0;
  #pragma unroll
  for (int j = 0; j < 8; ++j){
    int c = segCnt[seg*8 + j];
    if (j < e) off += c;
    if (j == e) cnt = c;
  }
  const int* list = segBucket + seg*256 + off;

  const char* wTe = (const char*)wT2 + e*131072;
  char* AB  = (char*)A;
  char* OSB = (char*)OS;

  for (int t0 = 0; t0 < cnt; t0 += 32){
    int rowsV = cnt - t0; if (rowsV > 32) rowsV = 32;
    __syncthreads();                    // protect toks/OS from previous iteration readers
    if (tid < 32)
      toks[tid] = list[t0 + (tid < rowsV ? tid : rowsV - 1)];
    __syncthreads();

    // ---- stage A: 8 threads per token row, 64B each, reg->LDS swizzled ----
    {
      int row = tid >> 3, ck = tid & 7;
      const char* src = (const char*)xT + toks[row]*512 + ck*64;
      s8v v0 = *(const s8v*)(src);
      s8v v1 = *(const s8v*)(src + 16);
      s8v v2 = *(const s8v*)(src + 32);
      s8v v3 = *(const s8v*)(src + 48);
      int base = row*512, swz = (row & 7) << 4;
      *(s8v*)(AB + base + ((ck*64 +  0) ^ swz)) = v0;
      *(s8v*)(AB + base + ((ck*64 + 16) ^ swz)) = v1;
      *(s8v*)(AB + base + ((ck*64 + 32) ^ swz)) = v2;
      *(s8v*)(AB + base + ((ck*64 + 48) ^ swz)) = v3;
    }
    __syncthreads();

    f4v acc[2][4];
    #pragma unroll
    for (int mi = 0; mi < 2; ++mi)
      #pragma unroll
      for (int ni = 0; ni < 4; ++ni) acc[mi][ni] = (f4v){0.f,0.f,0.f,0.f};

    int aswz = (l15 & 7) << 4;
    #pragma unroll
    for (int kc = 0; kc < 8; ++kc){
      s8v a0 = *(const s8v*)(AB + l15*512        + ((kc*64 + lq*16) ^ aswz));
      s8v a1 = *(const s8v*)(AB + (16 + l15)*512 + ((kc*64 + lq*16) ^ aswz));
      #pragma unroll
      for (int ni = 0; ni < 4; ++ni){
        int n = wv*64 + ni*16 + l15;
        s8v bv = *(const s8v*)(wTe + kc*16384 + n*64 + lq*16);
        acc[0][ni] = __builtin_amdgcn_mfma_f32_16x16x32_bf16(a0, bv, acc[0][ni], 0, 0, 0);
        acc[1][ni] = __builtin_amdgcn_mfma_f32_16x16x32_bf16(a1, bv, acc[1][ni], 0, 0, 0);
      }
    }

    // ---- epilogue: bias + residual + rate-mask -> OS (bf16) ----
    #pragma unroll
    for (int mi = 0; mi < 2; ++mi){
      #pragma unroll
      for (int ni = 0; ni < 4; ++ni){
        int col = wv*64 + ni*16 + l15;
        float bs = biasS[col];
        bool keep = col < rate_e;
        #pragma unroll
        for (int r = 0; r < 4; ++r){
          int row = mi*16 + lq*4 + r;
          float xres = b2f(*(const short*)(AB + row*512 + ((col*2) ^ ((row & 7) << 4))));
          float val  = keep ? (acc[mi][ni][r] + xres + bs) : 0.0f;
          *(short*)(OSB + row*512 + ((col*2) ^ ((row & 3) << 5))) = f2b(val);
        }
      }
    }
    __syncthreads();
    // ---- burst store: content at (row, off) belongs to col*2 = off ^ ((row&3)<<5) ----
    #pragma unroll
    for (int r2 = 0; r2 < 4; ++r2){
      int q = r2*4096 + tid*16;
      int row = q >> 9, off2 = q & 511;
      if (row < rowsV)
        *(s8v*)((char*)yT + toks[row]*512 + (off2 ^ ((row & 3) << 5))) = *(const s8v*)(OSB + q);
    }
  }
}

// K3: yT token-major bf16 (pre-masked) -> outx/outm (B,C,S) fp32.
// R11 load/transpose (s4v yT reads, scalar b32 LDS ops, [64][65] pad — alignment-safe,
// conflict-free). CHANGED: output phase uses float4 (16B) stores for BOTH outputs
// (R11 did 32 scalar 4B stores/thread on a 33.6MB write stream — the G13 violation).
__global__ __launch_bounds__(256) void k_final(const short* __restrict__ yT, const int* __restrict__ idx,
                                               const int* __restrict__ rate_choice,
                                               float* __restrict__ outx, float* __restrict__ outm){
  int bid = blockIdx.x;
  int b  = bid >> 7;
  int ct = (bid >> 5) & 3;
  int st = bid & 31;
  __shared__ float tile[64][65];    // [c-local][s-local]
  __shared__ int rateS[64];
  int tid = threadIdx.x;
  if (tid < 64) rateS[tid] = rate_choice[idx[b*S_ + st*64 + tid] & 7] >> 5;
  #pragma unroll
  for (int it = 0; it < 4; ++it){
    int srow = it*16 + (tid >> 4);
    int c4   = tid & 15;
    s4v v = *(const s4v*)(yT + (b*S_ + st*64 + srow)*C_ + ct*64 + c4*4);
    tile[c4*4+0][srow] = b2f(v[0]); tile[c4*4+1][srow] = b2f(v[1]);
    tile[c4*4+2][srow] = b2f(v[2]); tile[c4*4+3][srow] = b2f(v[3]);
  }
  __syncthreads();
  {
    int sv  = (tid & 15)*4;         // 4 consecutive s per lane (lane-fast -> 256B runs)
    int cq  = tid >> 4;             // 16 c-rows per iteration
    float* ob = outx + b*(C_*S_) + st*64;
    float* om = outm + b*(C_*S_) + st*64;
    float4 mv_lo, mv_hi;            // masks depend only on s and (cg>>5); cg>>5 = ct*2 + (cl>=32)
    {
      int mk = ct*2;
      mv_lo.x = (mk < rateS[sv+0]) ? 1.0f : 0.0f;
      mv_lo.y = (mk < rateS[sv+1]) ? 1.0f : 0.0f;
      mv_lo.z = (mk < rateS[sv+2]) ? 1.0f : 0.0f;
      mv_lo.w = (mk < rateS[sv+3]) ? 1.0f : 0.0f;
      ++mk;
      mv_hi.x = (mk < rateS[sv+0]) ? 1.0f : 0.0f;
      mv_hi.y = (mk < rateS[sv+1]) ? 1.0f : 0.0f;
      mv_hi.z = (mk < rateS[sv+2]) ? 1.0f : 0.0f;
      mv_hi.w = (mk < rateS[sv+3]) ? 1.0f : 0.0f;
    }
    #pragma unroll
    for (int it = 0; it < 4; ++it){
      int cl = it*16 + cq;
      int cg = ct*64 + cl;
      float4 ov;
      ov.x = tile[cl][sv+0]; ov.y = tile[cl][sv+1];
      ov.z = tile[cl][sv+2]; ov.w = tile[cl][sv+3];
      *(float4*)(ob + cg*S_ + sv) = ov;
      *(float4*)(om + cg*S_ + sv) = (cl < 32) ? mv_lo : mv_hi;
    }
  }
}

extern "C" void kernel_launch(void* const* d_in, const int* in_sizes, int n_in,
                              void* d_out, int out_size, void* d_ws, size_t ws_size,
                              hipStream_t stream){
  const float* x    = (const float*)d_in[0];
  const int*   idx  = (const int*)d_in[1];
  const float* wgt  = (const float*)d_in[2];
  const float* bias = (const float*)d_in[3];
  const int*   rate = (const int*)d_in[4];

  char* ws = (char*)d_ws;
  short* xT        = (short*)ws;                 // 8 MB token-major bf16
  short* wT2       = (short*)(ws + 8388608);     // 1 MB tiled weights [r][kc][n][k32]
  int*   segBucket = (int*)  (ws + 9437184);     // 64 KB (e-sorted per 256-token segment)
  int*   segCnt    = (int*)  (ws + 9502720);     // 2 KB  (64 segs x 8 experts)
  short* yT        = (short*)(ws + 10485760);    // 8 MB token-major bf16 (masked y)

  float* outx    = (float*)d_out;
  float* outm    = outx + (B_*C_*S_);
  float* idx_out = outx + 2*(B_*C_*S_);

  k_pre  <<<1216, 256, 0, stream>>>(x, xT, wgt, wT2, idx, segCnt, segBucket, idx_out);
  k_gemm <<<512,  256, 0, stream>>>(xT, wT2, bias, segCnt, segBucket, rate, yT);
  k_final<<<1024, 256, 0, stream>>>(yT, idx, rate, outx, outm);
}

// Round 19
// 35.194 us; speedup vs baseline: 1.0595x; 1.0595x over previous
//
#include <hip/hip_runtime.h>

#define B_ 8
#define C_ 256
#define S_ 2048
#define T_ (B_*S_)      // 16384 tokens

typedef short s8v __attribute__((ext_vector_type(8)));
typedef short s4v __attribute__((ext_vector_type(4)));
typedef float f4v __attribute__((ext_vector_type(4)));

__device__ inline short f2b(float f){            // fp32 -> bf16 RNE
  unsigned u = __builtin_bit_cast(unsigned, f);
  unsigned r = (u + 0x7FFFu + ((u >> 16) & 1u)) >> 16;
  return (short)r;
}
__device__ inline float b2f(short s){
  unsigned u = ((unsigned)(unsigned short)s) << 16;
  return __builtin_bit_cast(float, u);
}

// K1: fused prep, 1216 blocks, no global atomics (R11 proven).
//  0-1023:    x (B,C,S) fp32 -> xT token-major bf16 (LDS tile transpose)
//  1024-1151: weight (R,C,M) fp32 -> wT2 bf16 tiled [r][kc 8][n 256][k32]
//  1152-1215: counting sort per 256-token segment (block-local, deterministic)
__global__ __launch_bounds__(256) void k_pre(const float* __restrict__ x, short* __restrict__ xT,
                                             const float* __restrict__ wgt, short* __restrict__ wT2,
                                             const int* __restrict__ idx, int* __restrict__ segCnt,
                                             int* __restrict__ segBucket, float* __restrict__ idx_out){
  __shared__ float tile[64][65];
  int tid = threadIdx.x;
  int bid = blockIdx.x;

  if (bid < 1024){
    int b  = bid >> 7;
    int ct = (bid >> 5) & 3;
    int st = bid & 31;
    const float* xb = x + b*(C_*S_);
    #pragma unroll
    for (int it = 0; it < 4; ++it){
      int row = it*16 + (tid >> 4);       // c-local
      int s4  = tid & 15;
      float4 v = *(const float4*)(xb + (ct*64 + row)*S_ + st*64 + s4*4);
      tile[row][s4*4+0] = v.x; tile[row][s4*4+1] = v.y;
      tile[row][s4*4+2] = v.z; tile[row][s4*4+3] = v.w;
    }
    __syncthreads();
    #pragma unroll
    for (int it = 0; it < 4; ++it){
      int srow = it*16 + (tid >> 4);      // s-local
      int c4   = tid & 15;
      s4v o;
      o[0] = f2b(tile[c4*4+0][srow]); o[1] = f2b(tile[c4*4+1][srow]);
      o[2] = f2b(tile[c4*4+2][srow]); o[3] = f2b(tile[c4*4+3][srow]);
      *(s4v*)(xT + (b*S_ + st*64 + srow)*C_ + ct*64 + c4*4) = o;
    }
  } else if (bid < 1152){
    int wb_ = bid - 1024;
    int r  = wb_ >> 4;
    int ct = (wb_ >> 2) & 3;   // c-tile (K dim)
    int mt = wb_ & 3;          // n-tile
    const float* wsrc = wgt + r*(C_*256);
    #pragma unroll
    for (int it = 0; it < 4; ++it){
      int row = it*16 + (tid >> 4);       // c-local
      int m4  = tid & 15;
      float4 v = *(const float4*)(wsrc + (ct*64 + row)*256 + mt*64 + m4*4);
      tile[row][m4*4+0] = v.x; tile[row][m4*4+1] = v.y;
      tile[row][m4*4+2] = v.z; tile[row][m4*4+3] = v.w;
    }
    __syncthreads();
    char* wdst = (char*)wT2 + r*131072;
    #pragma unroll
    for (int it = 0; it < 2; ++it){
      int q  = it*256 + tid;
      int ml = q >> 3;                    // n-local
      int ck = q & 7;                     // 8 consecutive c
      int mg = mt*64 + ml;
      int cg = ct*64 + ck*8;
      int kcb = cg >> 5, klocal = cg & 31;
      s8v o;
      #pragma unroll
      for (int j = 0; j < 8; ++j) o[j] = f2b(tile[ck*8 + j][ml]);
      *(s8v*)(wdst + kcb*16384 + mg*64 + klocal*2) = o;   // linear [kc][n][k32]
    }
  } else {
    int seg = bid - 1152;
    __shared__ int lcount[8];
    __shared__ int lbase[8];
    int t = seg*256 + tid;
    if (tid < 8) lcount[tid] = 0;
    __syncthreads();
    int ei = idx[t];
    int e  = ei & 7;
    int lp = atomicAdd(&lcount[e], 1);    // LDS atomic, block-local
    __syncthreads();
    if (tid == 0){
      int a0 = 0;
      #pragma unroll
      for (int e2 = 0; e2 < 8; ++e2){ lbase[e2] = a0; a0 += lcount[e2]; }
    }
    __syncthreads();
    if (tid < 8) segCnt[seg*8 + tid] = lcount[tid];
    segBucket[seg*256 + lbase[e] + lp] = t;
    idx_out[t] = (float)ei;
  }
}

// K2: grouped GEMM — R11 proven body. Block = (segment, expert), bid&7=e -> XCD-local W.
// A reg->LDS swizzled; B direct global->VGPR from L2-resident wT2; barrier-free K-loop;
// fused bias+residual+rate-mask epilogue -> OS restage -> burst yT writes.
__global__ __launch_bounds__(256,2) void k_gemm(const short* __restrict__ xT, const short* __restrict__ wT2,
                                                const float* __restrict__ bias, const int* __restrict__ segCnt,
                                                const int* __restrict__ segBucket, const int* __restrict__ rate,
                                                short* __restrict__ yT){
  int bid = blockIdx.x;
  int e   = bid & 7;
  int seg = bid >> 3;

  __shared__ short A [32*256];     // 16KB
  __shared__ short OS[32*256];     // 16KB out-stage
  __shared__ float biasS[256];
  __shared__ int   toks[32];

  int tid  = threadIdx.x;
  int lane = tid & 63, wv = tid >> 6;
  int l15  = lane & 15, lq = lane >> 4;

  biasS[tid] = bias[e*256 + tid];
  int rate_e = rate[e];

  int off = 0, cnt = 0;
  #pragma unroll
  for (int j = 0; j < 8; ++j){
    int c = segCnt[seg*8 + j];
    if (j < e) off += c;
    if (j == e) cnt = c;
  }
  const int* list = segBucket + seg*256 + off;

  const char* wTe = (const char*)wT2 + e*131072;
  char* AB  = (char*)A;
  char* OSB = (char*)OS;

  for (int t0 = 0; t0 < cnt; t0 += 32){
    int rowsV = cnt - t0; if (rowsV > 32) rowsV = 32;
    __syncthreads();                    // protect toks/OS from previous iteration readers
    if (tid < 32)
      toks[tid] = list[t0 + (tid < rowsV ? tid : rowsV - 1)];
    __syncthreads();

    // ---- stage A: 8 threads per token row, 64B each, reg->LDS swizzled ----
    {
      int row = tid >> 3, ck = tid & 7;
      const char* src = (const char*)xT + toks[row]*512 + ck*64;
      s8v v0 = *(const s8v*)(src);
      s8v v1 = *(const s8v*)(src + 16);
      s8v v2 = *(const s8v*)(src + 32);
      s8v v3 = *(const s8v*)(src + 48);
      int base = row*512, swz = (row & 7) << 4;
      *(s8v*)(AB + base + ((ck*64 +  0) ^ swz)) = v0;
      *(s8v*)(AB + base + ((ck*64 + 16) ^ swz)) = v1;
      *(s8v*)(AB + base + ((ck*64 + 32) ^ swz)) = v2;
      *(s8v*)(AB + base + ((ck*64 + 48) ^ swz)) = v3;
    }
    __syncthreads();

    f4v acc[2][4];
    #pragma unroll
    for (int mi = 0; mi < 2; ++mi)
      #pragma unroll
      for (int ni = 0; ni < 4; ++ni) acc[mi][ni] = (f4v){0.f,0.f,0.f,0.f};

    int aswz = (l15 & 7) << 4;
    #pragma unroll
    for (int kc = 0; kc < 8; ++kc){
      s8v a0 = *(const s8v*)(AB + l15*512        + ((kc*64 + lq*16) ^ aswz));
      s8v a1 = *(const s8v*)(AB + (16 + l15)*512 + ((kc*64 + lq*16) ^ aswz));
      #pragma unroll
      for (int ni = 0; ni < 4; ++ni){
        int n = wv*64 + ni*16 + l15;
        s8v bv = *(const s8v*)(wTe + kc*16384 + n*64 + lq*16);
        acc[0][ni] = __builtin_amdgcn_mfma_f32_16x16x32_bf16(a0, bv, acc[0][ni], 0, 0, 0);
        acc[1][ni] = __builtin_amdgcn_mfma_f32_16x16x32_bf16(a1, bv, acc[1][ni], 0, 0, 0);
      }
    }

    // ---- epilogue: bias + residual + rate-mask -> OS (bf16) ----
    #pragma unroll
    for (int mi = 0; mi < 2; ++mi){
      #pragma unroll
      for (int ni = 0; ni < 4; ++ni){
        int col = wv*64 + ni*16 + l15;
        float bs = biasS[col];
        bool keep = col < rate_e;
        #pragma unroll
        for (int r = 0; r < 4; ++r){
          int row = mi*16 + lq*4 + r;
          float xres = b2f(*(const short*)(AB + row*512 + ((col*2) ^ ((row & 7) << 4))));
          float val  = keep ? (acc[mi][ni][r] + xres + bs) : 0.0f;
          *(short*)(OSB + row*512 + ((col*2) ^ ((row & 3) << 5))) = f2b(val);
        }
      }
    }
    __syncthreads();
    // ---- burst store: content at (row, off) belongs to col*2 = off ^ ((row&3)<<5) ----
    #pragma unroll
    for (int r2 = 0; r2 < 4; ++r2){
      int q = r2*4096 + tid*16;
      int row = q >> 9, off2 = q & 511;
      if (row < rowsV)
        *(s8v*)((char*)yT + toks[row]*512 + (off2 ^ ((row & 3) << 5))) = *(const s8v*)(OSB + q);
    }
  }
}

// K3: yT token-major bf16 (pre-masked) -> outx (B,C,S) fp32 + outm (R11 proven).
__global__ __launch_bounds__(256) void k_final(const short* __restrict__ yT, const int* __restrict__ idx,
                                               const int* __restrict__ rate_choice,
                                               float* __restrict__ outx, float* __restrict__ outm){
  int bid = blockIdx.x;
  int b  = bid >> 7;
  int ct = (bid >> 5) & 3;
  int st = bid & 31;
  __shared__ float tile[64][65];
  __shared__ int rateS[64];
  int tid = threadIdx.x;
  if (tid < 64) rateS[tid] = rate_choice[idx[b*S_ + st*64 + tid] & 7] >> 5;
  #pragma unroll
  for (int it = 0; it < 4; ++it){
    int srow = it*16 + (tid >> 4);
    int c4   = tid & 15;
    s4v v = *(const s4v*)(yT + (b*S_ + st*64 + srow)*C_ + ct*64 + c4*4);
    tile[c4*4+0][srow] = b2f(v[0]); tile[c4*4+1][srow] = b2f(v[1]);
    tile[c4*4+2][srow] = b2f(v[2]); tile[c4*4+3][srow] = b2f(v[3]);
  }
  __syncthreads();
  #pragma unroll
  for (int it = 0; it < 16; ++it){
    int cl = it*4 + (tid >> 6);
    int sl = tid & 63;
    int cg = ct*64 + cl;
    float v = tile[cl][sl];
    bool keep = (cg >> 5) < rateS[sl];
    int off = b*(C_*S_) + cg*S_ + st*64 + sl;
    outx[off] = v;                      // yT pre-masked in k_gemm
    outm[off] = keep ? 1.0f : 0.0f;
  }
}

extern "C" void kernel_launch(void* const* d_in, const int* in_sizes, int n_in,
                              void* d_out, int out_size, void* d_ws, size_t ws_size,
                              hipStream_t stream){
  const float* x    = (const float*)d_in[0];
  const int*   idx  = (const int*)d_in[1];
  const float* wgt  = (const float*)d_in[2];
  const float* bias = (const float*)d_in[3];
  const int*   rate = (const int*)d_in[4];

  char* ws = (char*)d_ws;
  short* xT        = (short*)ws;                 // 8 MB token-major bf16
  short* wT2       = (short*)(ws + 8388608);     // 1 MB tiled weights [r][kc][n][k32]
  int*   segBucket = (int*)  (ws + 9437184);     // 64 KB (e-sorted per 256-token segment)
  int*   segCnt    = (int*)  (ws + 9502720);     // 2 KB  (64 segs x 8 experts)
  short* yT        = (short*)(ws + 10485760);    // 8 MB token-major bf16 (masked y)

  float* outx    = (float*)d_out;
  float* outm    = outx + (B_*C_*S_);
  float* idx_out = outx + 2*(B_*C_*S_);

  k_pre  <<<1216, 256, 0, stream>>>(x, xT, wgt, wT2, idx, segCnt, segBucket, idx_out);
  k_gemm <<<512,  256, 0, stream>>>(xT, wT2, bias, segCnt, segBucket, rate, yT);
  k_final<<<1024, 256, 0, stream>>>(yT, idx, rate, outx, outm);
}

// Round 20
// 34.610 us; speedup vs baseline: 1.0774x; 1.0169x over previous
//
#include <hip/hip_runtime.h>

#define B_ 8
#define C_ 256
#define S_ 2048
#define T_ (B_*S_)      // 16384 tokens

typedef short s8v __attribute__((ext_vector_type(8)));
typedef short s4v __attribute__((ext_vector_type(4)));
typedef float f4v __attribute__((ext_vector_type(4)));

__device__ inline short f2b(float f){            // fp32 -> bf16 RNE
  unsigned u = __builtin_bit_cast(unsigned, f);
  unsigned r = (u + 0x7FFFu + ((u >> 16) & 1u)) >> 16;
  return (short)r;
}
__device__ inline float b2f(short s){
  unsigned u = ((unsigned)(unsigned short)s) << 16;
  return __builtin_bit_cast(float, u);
}

// K1: fused prep, 1216 blocks, no global atomics (R11 proven + outm fused into the
// x-transpose blocks: outm depends only on idx/rate, so it needn't wait for the GEMM;
// its 16.8MB of streaming writes overlap the transpose's latency stalls).
__global__ __launch_bounds__(256) void k_pre(const float* __restrict__ x, short* __restrict__ xT,
                                             const float* __restrict__ wgt, short* __restrict__ wT2,
                                             const int* __restrict__ idx, const int* __restrict__ rate,
                                             int* __restrict__ segCnt, int* __restrict__ segBucket,
                                             float* __restrict__ idx_out, float* __restrict__ outm){
  __shared__ float tile[64][65];
  __shared__ int rateS[64];
  int tid = threadIdx.x;
  int bid = blockIdx.x;

  if (bid < 1024){
    int b  = bid >> 7;
    int ct = (bid >> 5) & 3;
    int st = bid & 31;
    if (tid < 64) rateS[tid] = rate[idx[b*S_ + st*64 + tid] & 7] >> 5;
    const float* xb = x + b*(C_*S_);
    #pragma unroll
    for (int it = 0; it < 4; ++it){
      int row = it*16 + (tid >> 4);       // c-local
      int s4  = tid & 15;
      float4 v = *(const float4*)(xb + (ct*64 + row)*S_ + st*64 + s4*4);
      tile[row][s4*4+0] = v.x; tile[row][s4*4+1] = v.y;
      tile[row][s4*4+2] = v.z; tile[row][s4*4+3] = v.w;
    }
    __syncthreads();                      // covers tile AND rateS
    #pragma unroll
    for (int it = 0; it < 4; ++it){
      int srow = it*16 + (tid >> 4);      // s-local
      int c4   = tid & 15;
      s4v o;
      o[0] = f2b(tile[c4*4+0][srow]); o[1] = f2b(tile[c4*4+1][srow]);
      o[2] = f2b(tile[c4*4+2][srow]); o[3] = f2b(tile[c4*4+3][srow]);
      *(s4v*)(xT + (b*S_ + st*64 + srow)*C_ + ct*64 + c4*4) = o;
    }
    // ---- outm for this (64c, 64s) tile: mask = (cg>>5 < rate32[s]) ----
    {
      int sv = (tid & 15)*4;              // lane-fast in s -> 256B runs
      int cq = tid >> 4;
      float* om = outm + b*(C_*S_) + st*64;
      #pragma unroll
      for (int it = 0; it < 4; ++it){
        int cl = it*16 + cq;
        int cg = ct*64 + cl;
        int mk = cg >> 5;
        float4 mv;
        mv.x = (mk < rateS[sv+0]) ? 1.0f : 0.0f;
        mv.y = (mk < rateS[sv+1]) ? 1.0f : 0.0f;
        mv.z = (mk < rateS[sv+2]) ? 1.0f : 0.0f;
        mv.w = (mk < rateS[sv+3]) ? 1.0f : 0.0f;
        *(float4*)(om + cg*S_ + sv) = mv;
      }
    }
  } else if (bid < 1152){
    int wb_ = bid - 1024;
    int r  = wb_ >> 4;
    int ct = (wb_ >> 2) & 3;   // c-tile (K dim)
    int mt = wb_ & 3;          // n-tile
    const float* wsrc = wgt + r*(C_*256);
    #pragma unroll
    for (int it = 0; it < 4; ++it){
      int row = it*16 + (tid >> 4);       // c-local
      int m4  = tid & 15;
      float4 v = *(const float4*)(wsrc + (ct*64 + row)*256 + mt*64 + m4*4);
      tile[row][m4*4+0] = v.x; tile[row][m4*4+1] = v.y;
      tile[row][m4*4+2] = v.z; tile[row][m4*4+3] = v.w;
    }
    __syncthreads();
    char* wdst = (char*)wT2 + r*131072;
    #pragma unroll
    for (int it = 0; it < 2; ++it){
      int q  = it*256 + tid;
      int ml = q >> 3;                    // n-local
      int ck = q & 7;                     // 8 consecutive c
      int mg = mt*64 + ml;
      int cg = ct*64 + ck*8;
      int kcb = cg >> 5, klocal = cg & 31;
      s8v o;
      #pragma unroll
      for (int j = 0; j < 8; ++j) o[j] = f2b(tile[ck*8 + j][ml]);
      *(s8v*)(wdst + kcb*16384 + mg*64 + klocal*2) = o;   // linear [kc][n][k32]
    }
  } else {
    int seg = bid - 1152;
    __shared__ int lcount[8];
    __shared__ int lbase[8];
    int t = seg*256 + tid;
    if (tid < 8) lcount[tid] = 0;
    __syncthreads();
    int ei = idx[t];
    int e  = ei & 7;
    int lp = atomicAdd(&lcount[e], 1);    // LDS atomic, block-local
    __syncthreads();
    if (tid == 0){
      int a0 = 0;
      #pragma unroll
      for (int e2 = 0; e2 < 8; ++e2){ lbase[e2] = a0; a0 += lcount[e2]; }
    }
    __syncthreads();
    if (tid < 8) segCnt[seg*8 + tid] = lcount[tid];
    segBucket[seg*256 + lbase[e] + lp] = t;
    idx_out[t] = (float)ei;
  }
}

// K2: grouped GEMM — EXACT R11/R19 body (proven best).
__global__ __launch_bounds__(256,2) void k_gemm(const short* __restrict__ xT, const short* __restrict__ wT2,
                                                const float* __restrict__ bias, const int* __restrict__ segCnt,
                                                const int* __restrict__ segBucket, const int* __restrict__ rate,
                                                short* __restrict__ yT){
  int bid = blockIdx.x;
  int e   = bid & 7;
  int seg = bid >> 3;

  __shared__ short A [32*256];     // 16KB
  __shared__ short OS[32*256];     // 16KB out-stage
  __shared__ float biasS[256];
  __shared__ int   toks[32];

  int tid  = threadIdx.x;
  int lane = tid & 63, wv = tid >> 6;
  int l15  = lane & 15, lq = lane >> 4;

  biasS[tid] = bias[e*256 + tid];
  int rate_e = rate[e];

  int off = 0, cnt = 0;
  #pragma unroll
  for (int j = 0; j < 8; ++j){
    int c = segCnt[seg*8 + j];
    if (j < e) off += c;
    if (j == e) cnt = c;
  }
  const int* list = segBucket + seg*256 + off;

  const char* wTe = (const char*)wT2 + e*131072;
  char* AB  = (char*)A;
  char* OSB = (char*)OS;

  for (int t0 = 0; t0 < cnt; t0 += 32){
    int rowsV = cnt - t0; if (rowsV > 32) rowsV = 32;
    __syncthreads();                    // protect toks/OS from previous iteration readers
    if (tid < 32)
      toks[tid] = list[t0 + (tid < rowsV ? tid : rowsV - 1)];
    __syncthreads();

    // ---- stage A: 8 threads per token row, 64B each, reg->LDS swizzled ----
    {
      int row = tid >> 3, ck = tid & 7;
      const char* src = (const char*)xT + toks[row]*512 + ck*64;
      s8v v0 = *(const s8v*)(src);
      s8v v1 = *(const s8v*)(src + 16);
      s8v v2 = *(const s8v*)(src + 32);
      s8v v3 = *(const s8v*)(src + 48);
      int base = row*512, swz = (row & 7) << 4;
      *(s8v*)(AB + base + ((ck*64 +  0) ^ swz)) = v0;
      *(s8v*)(AB + base + ((ck*64 + 16) ^ swz)) = v1;
      *(s8v*)(AB + base + ((ck*64 + 32) ^ swz)) = v2;
      *(s8v*)(AB + base + ((ck*64 + 48) ^ swz)) = v3;
    }
    __syncthreads();

    f4v acc[2][4];
    #pragma unroll
    for (int mi = 0; mi < 2; ++mi)
      #pragma unroll
      for (int ni = 0; ni < 4; ++ni) acc[mi][ni] = (f4v){0.f,0.f,0.f,0.f};

    int aswz = (l15 & 7) << 4;
    #pragma unroll
    for (int kc = 0; kc < 8; ++kc){
      s8v a0 = *(const s8v*)(AB + l15*512        + ((kc*64 + lq*16) ^ aswz));
      s8v a1 = *(const s8v*)(AB + (16 + l15)*512 + ((kc*64 + lq*16) ^ aswz));
      #pragma unroll
      for (int ni = 0; ni < 4; ++ni){
        int n = wv*64 + ni*16 + l15;
        s8v bv = *(const s8v*)(wTe + kc*16384 + n*64 + lq*16);
        acc[0][ni] = __builtin_amdgcn_mfma_f32_16x16x32_bf16(a0, bv, acc[0][ni], 0, 0, 0);
        acc[1][ni] = __builtin_amdgcn_mfma_f32_16x16x32_bf16(a1, bv, acc[1][ni], 0, 0, 0);
      }
    }

    // ---- epilogue: bias + residual + rate-mask -> OS (bf16) ----
    #pragma unroll
    for (int mi = 0; mi < 2; ++mi){
      #pragma unroll
      for (int ni = 0; ni < 4; ++ni){
        int col = wv*64 + ni*16 + l15;
        float bs = biasS[col];
        bool keep = col < rate_e;
        #pragma unroll
        for (int r = 0; r < 4; ++r){
          int row = mi*16 + lq*4 + r;
          float xres = b2f(*(const short*)(AB + row*512 + ((col*2) ^ ((row & 7) << 4))));
          float val  = keep ? (acc[mi][ni][r] + xres + bs) : 0.0f;
          *(short*)(OSB + row*512 + ((col*2) ^ ((row & 3) << 5))) = f2b(val);
        }
      }
    }
    __syncthreads();
    // ---- burst store: content at (row, off) belongs to col*2 = off ^ ((row&3)<<5) ----
    #pragma unroll
    for (int r2 = 0; r2 < 4; ++r2){
      int q = r2*4096 + tid*16;
      int row = q >> 9, off2 = q & 511;
      if (row < rowsV)
        *(s8v*)((char*)yT + toks[row]*512 + (off2 ^ ((row & 3) << 5))) = *(const s8v*)(OSB + q);
    }
  }
}

// K3: yT token-major bf16 (pre-masked) -> outx (B,C,S) fp32 ONLY (outm moved to k_pre).
// R11 proven body minus the outm stream and idx/rate reads.
__global__ __launch_bounds__(256) void k_final(const short* __restrict__ yT,
                                               float* __restrict__ outx){
  int bid = blockIdx.x;
  int b  = bid >> 7;
  int ct = (bid >> 5) & 3;
  int st = bid & 31;
  __shared__ float tile[64][65];
  int tid = threadIdx.x;
  #pragma unroll
  for (int it = 0; it < 4; ++it){
    int srow = it*16 + (tid >> 4);
    int c4   = tid & 15;
    s4v v = *(const s4v*)(yT + (b*S_ + st*64 + srow)*C_ + ct*64 + c4*4);
    tile[c4*4+0][srow] = b2f(v[0]); tile[c4*4+1][srow] = b2f(v[1]);
    tile[c4*4+2][srow] = b2f(v[2]); tile[c4*4+3][srow] = b2f(v[3]);
  }
  __syncthreads();
  #pragma unroll
  for (int it = 0; it < 16; ++it){
    int cl = it*4 + (tid >> 6);
    int sl = tid & 63;
    int cg = ct*64 + cl;
    outx[b*(C_*S_) + cg*S_ + st*64 + sl] = tile[cl][sl];   // yT pre-masked in k_gemm
  }
}

extern "C" void kernel_launch(void* const* d_in, const int* in_sizes, int n_in,
                              void* d_out, int out_size, void* d_ws, size_t ws_size,
                              hipStream_t stream){
  const float* x    = (const float*)d_in[0];
  const int*   idx  = (const int*)d_in[1];
  const float* wgt  = (const float*)d_in[2];
  const float* bias = (const float*)d_in[3];
  const int*   rate = (const int*)d_in[4];

  char* ws = (char*)d_ws;
  short* xT        = (short*)ws;                 // 8 MB token-major bf16
  short* wT2       = (short*)(ws + 8388608);     // 1 MB tiled weights [r][kc][n][k32]
  int*   segBucket = (int*)  (ws + 9437184);     // 64 KB (e-sorted per 256-token segment)
  int*   segCnt    = (int*)  (ws + 9502720);     // 2 KB  (64 segs x 8 experts)
  short* yT        = (short*)(ws + 10485760);    // 8 MB token-major bf16 (masked y)

  float* outx    = (float*)d_out;
  float* outm    = outx + (B_*C_*S_);
  float* idx_out = outx + 2*(B_*C_*S_);

  k_pre  <<<1216, 256, 0, stream>>>(x, xT, wgt, wT2, idx, rate, segCnt, segBucket, idx_out, outm);
  k_gemm <<<512,  256, 0, stream>>>(xT, wT2, bias, segCnt, segBucket, rate, yT);
  k_final<<<1024, 256, 0, stream>>>(yT, outx);
}

// Round 22
// 34.602 us; speedup vs baseline: 1.0776x; 1.0002x over previous
//
#include <hip/hip_runtime.h>

#define B_ 8
#define C_ 256
#define S_ 2048
#define T_ (B_*S_)      // 16384 tokens

typedef short s8v __attribute__((ext_vector_type(8)));
typedef short s4v __attribute__((ext_vector_type(4)));
typedef float f4v __attribute__((ext_vector_type(4)));

__device__ inline short f2b(float f){            // fp32 -> bf16 RNE
  unsigned u = __builtin_bit_cast(unsigned, f);
  unsigned r = (u + 0x7FFFu + ((u >> 16) & 1u)) >> 16;
  return (short)r;
}
__device__ inline float b2f(short s){
  unsigned u = ((unsigned)(unsigned short)s) << 16;
  return __builtin_bit_cast(float, u);
}

// K1: fused prep, 1216 blocks, no global atomics (R20 proven best).
//  0-1023:    x (B,C,S) fp32 -> xT token-major bf16 (LDS tile transpose) + outm writes
//  1024-1151: weight (R,C,M) fp32 -> wT2 bf16 tiled [r][kc 8][n 256][k32]
//  1152-1215: counting sort per 256-token segment (block-local, deterministic)
__global__ __launch_bounds__(256) void k_pre(const float* __restrict__ x, short* __restrict__ xT,
                                             const float* __restrict__ wgt, short* __restrict__ wT2,
                                             const int* __restrict__ idx, const int* __restrict__ rate,
                                             int* __restrict__ segCnt, int* __restrict__ segBucket,
                                             float* __restrict__ idx_out, float* __restrict__ outm){
  __shared__ float tile[64][65];
  __shared__ int rateS[64];
  int tid = threadIdx.x;
  int bid = blockIdx.x;

  if (bid < 1024){
    int b  = bid >> 7;
    int ct = (bid >> 5) & 3;
    int st = bid & 31;
    if (tid < 64) rateS[tid] = rate[idx[b*S_ + st*64 + tid] & 7] >> 5;
    const float* xb = x + b*(C_*S_);
    #pragma unroll
    for (int it = 0; it < 4; ++it){
      int row = it*16 + (tid >> 4);       // c-local
      int s4  = tid & 15;
      float4 v = *(const float4*)(xb + (ct*64 + row)*S_ + st*64 + s4*4);
      tile[row][s4*4+0] = v.x; tile[row][s4*4+1] = v.y;
      tile[row][s4*4+2] = v.z; tile[row][s4*4+3] = v.w;
    }
    __syncthreads();                      // covers tile AND rateS
    #pragma unroll
    for (int it = 0; it < 4; ++it){
      int srow = it*16 + (tid >> 4);      // s-local
      int c4   = tid & 15;
      s4v o;
      o[0] = f2b(tile[c4*4+0][srow]); o[1] = f2b(tile[c4*4+1][srow]);
      o[2] = f2b(tile[c4*4+2][srow]); o[3] = f2b(tile[c4*4+3][srow]);
      *(s4v*)(xT + (b*S_ + st*64 + srow)*C_ + ct*64 + c4*4) = o;
    }
    // ---- outm for this (64c, 64s) tile: mask = (cg>>5 < rate32[s]) ----
    {
      int sv = (tid & 15)*4;              // lane-fast in s -> 256B runs
      int cq = tid >> 4;
      float* om = outm + b*(C_*S_) + st*64;
      #pragma unroll
      for (int it = 0; it < 4; ++it){
        int cl = it*16 + cq;
        int cg = ct*64 + cl;
        int mk = cg >> 5;
        float4 mv;
        mv.x = (mk < rateS[sv+0]) ? 1.0f : 0.0f;
        mv.y = (mk < rateS[sv+1]) ? 1.0f : 0.0f;
        mv.z = (mk < rateS[sv+2]) ? 1.0f : 0.0f;
        mv.w = (mk < rateS[sv+3]) ? 1.0f : 0.0f;
        *(float4*)(om + cg*S_ + sv) = mv;
      }
    }
  } else if (bid < 1152){
    int wb_ = bid - 1024;
    int r  = wb_ >> 4;
    int ct = (wb_ >> 2) & 3;   // c-tile (K dim)
    int mt = wb_ & 3;          // n-tile
    const float* wsrc = wgt + r*(C_*256);
    #pragma unroll
    for (int it = 0; it < 4; ++it){
      int row = it*16 + (tid >> 4);       // c-local
      int m4  = tid & 15;
      float4 v = *(const float4*)(wsrc + (ct*64 + row)*256 + mt*64 + m4*4);
      tile[row][m4*4+0] = v.x; tile[row][m4*4+1] = v.y;
      tile[row][m4*4+2] = v.z; tile[row][m4*4+3] = v.w;
    }
    __syncthreads();
    char* wdst = (char*)wT2 + r*131072;
    #pragma unroll
    for (int it = 0; it < 2; ++it){
      int q  = it*256 + tid;
      int ml = q >> 3;                    // n-local
      int ck = q & 7;                     // 8 consecutive c
      int mg = mt*64 + ml;
      int cg = ct*64 + ck*8;
      int kcb = cg >> 5, klocal = cg & 31;
      s8v o;
      #pragma unroll
      for (int j = 0; j < 8; ++j) o[j] = f2b(tile[ck*8 + j][ml]);
      *(s8v*)(wdst + kcb*16384 + mg*64 + klocal*2) = o;   // linear [kc][n][k32]
    }
  } else {
    int seg = bid - 1152;
    __shared__ int lcount[8];
    __shared__ int lbase[8];
    int t = seg*256 + tid;
    if (tid < 8) lcount[tid] = 0;
    __syncthreads();
    int ei = idx[t];
    int e  = ei & 7;
    int lp = atomicAdd(&lcount[e], 1);    // LDS atomic, block-local
    __syncthreads();
    if (tid == 0){
      int a0 = 0;
      #pragma unroll
      for (int e2 = 0; e2 < 8; ++e2){ lbase[e2] = a0; a0 += lcount[e2]; }
    }
    __syncthreads();
    if (tid < 8) segCnt[seg*8 + tid] = lcount[tid];
    segBucket[seg*256 + lbase[e] + lp] = t;
    idx_out[t] = (float)ei;
  }
}

// K2: grouped GEMM — R11/R19/R20 proven body.
__global__ __launch_bounds__(256,2) void k_gemm(const short* __restrict__ xT, const short* __restrict__ wT2,
                                                const float* __restrict__ bias, const int* __restrict__ segCnt,
                                                const int* __restrict__ segBucket, const int* __restrict__ rate,
                                                short* __restrict__ yT){
  int bid = blockIdx.x;
  int e   = bid & 7;
  int seg = bid >> 3;

  __shared__ short A [32*256];     // 16KB
  __shared__ short OS[32*256];     // 16KB out-stage
  __shared__ float biasS[256];
  __shared__ int   toks[32];

  int tid  = threadIdx.x;
  int lane = tid & 63, wv = tid >> 6;
  int l15  = lane & 15, lq = lane >> 4;

  biasS[tid] = bias[e*256 + tid];
  int rate_e = rate[e];

  int off = 0, cnt = 0;
  #pragma unroll
  for (int j = 0; j < 8; ++j){
    int c = segCnt[seg*8 + j];
    if (j < e) off += c;
    if (j == e) cnt = c;
  }
  const int* list = segBucket + seg*256 + off;

  const char* wTe = (const char*)wT2 + e*131072;
  char* AB  = (char*)A;
  char* OSB = (char*)OS;

  for (int t0 = 0; t0 < cnt; t0 += 32){
    int rowsV = cnt - t0; if (rowsV > 32) rowsV = 32;
    __syncthreads();                    // protect toks/OS from previous iteration readers
    if (tid < 32)
      toks[tid] = list[t0 + (tid < rowsV ? tid : rowsV - 1)];
    __syncthreads();

    // ---- stage A: 8 threads per token row, 64B each, reg->LDS swizzled ----
    {
      int row = tid >> 3, ck = tid & 7;
      const char* src = (const char*)xT + toks[row]*512 + ck*64;
      s8v v0 = *(const s8v*)(src);
      s8v v1 = *(const s8v*)(src + 16);
      s8v v2 = *(const s8v*)(src + 32);
      s8v v3 = *(const s8v*)(src + 48);
      int base = row*512, swz = (row & 7) << 4;
      *(s8v*)(AB + base + ((ck*64 +  0) ^ swz)) = v0;
      *(s8v*)(AB + base + ((ck*64 + 16) ^ swz)) = v1;
      *(s8v*)(AB + base + ((ck*64 + 32) ^ swz)) = v2;
      *(s8v*)(AB + base + ((ck*64 + 48) ^ swz)) = v3;
    }
    __syncthreads();

    f4v acc[2][4];
    #pragma unroll
    for (int mi = 0; mi < 2; ++mi)
      #pragma unroll
      for (int ni = 0; ni < 4; ++ni) acc[mi][ni] = (f4v){0.f,0.f,0.f,0.f};

    int aswz = (l15 & 7) << 4;
    #pragma unroll
    for (int kc = 0; kc < 8; ++kc){
      s8v a0 = *(const s8v*)(AB + l15*512        + ((kc*64 + lq*16) ^ aswz));
      s8v a1 = *(const s8v*)(AB + (16 + l15)*512 + ((kc*64 + lq*16) ^ aswz));
      #pragma unroll
      for (int ni = 0; ni < 4; ++ni){
        int n = wv*64 + ni*16 + l15;
        s8v bv = *(const s8v*)(wTe + kc*16384 + n*64 + lq*16);
        acc[0][ni] = __builtin_amdgcn_mfma_f32_16x16x32_bf16(a0, bv, acc[0][ni], 0, 0, 0);
        acc[1][ni] = __builtin_amdgcn_mfma_f32_16x16x32_bf16(a1, bv, acc[1][ni], 0, 0, 0);
      }
    }

    // ---- epilogue: bias + residual + rate-mask -> OS (bf16) ----
    #pragma unroll
    for (int mi = 0; mi < 2; ++mi){
      #pragma unroll
      for (int ni = 0; ni < 4; ++ni){
        int col = wv*64 + ni*16 + l15;
        float bs = biasS[col];
        bool keep = col < rate_e;
        #pragma unroll
        for (int r = 0; r < 4; ++r){
          int row = mi*16 + lq*4 + r;
          float xres = b2f(*(const short*)(AB + row*512 + ((col*2) ^ ((row & 7) << 4))));
          float val  = keep ? (acc[mi][ni][r] + xres + bs) : 0.0f;
          *(short*)(OSB + row*512 + ((col*2) ^ ((row & 3) << 5))) = f2b(val);
        }
      }
    }
    __syncthreads();
    // ---- burst store: content at (row, off) belongs to col*2 = off ^ ((row&3)<<5) ----
    #pragma unroll
    for (int r2 = 0; r2 < 4; ++r2){
      int q = r2*4096 + tid*16;
      int row = q >> 9, off2 = q & 511;
      if (row < rowsV)
        *(s8v*)((char*)yT + toks[row]*512 + (off2 ^ ((row & 3) << 5))) = *(const s8v*)(OSB + q);
    }
  }
}

// K3: yT token-major bf16 (pre-masked) -> outx (B,C,S) fp32 ONLY (outm in k_pre).
__global__ __launch_bounds__(256) void k_final(const short* __restrict__ yT,
                                               float* __restrict__ outx){
  int bid = blockIdx.x;
  int b  = bid >> 7;
  int ct = (bid >> 5) & 3;
  int st = bid & 31;
  __shared__ float tile[64][65];
  int tid = threadIdx.x;
  #pragma unroll
  for (int it = 0; it < 4; ++it){
    int srow = it*16 + (tid >> 4);
    int c4   = tid & 15;
    s4v v = *(const s4v*)(yT + (b*S_ + st*64 + srow)*C_ + ct*64 + c4*4);
    tile[c4*4+0][srow] = b2f(v[0]); tile[c4*4+1][srow] = b2f(v[1]);
    tile[c4*4+2][srow] = b2f(v[2]); tile[c4*4+3][srow] = b2f(v[3]);
  }
  __syncthreads();
  #pragma unroll
  for (int it = 0; it < 16; ++it){
    int cl = it*4 + (tid >> 6);
    int sl = tid & 63;
    int cg = ct*64 + cl;
    outx[b*(C_*S_) + cg*S_ + st*64 + sl] = tile[cl][sl];   // yT pre-masked in k_gemm
  }
}

extern "C" void kernel_launch(void* const* d_in, const int* in_sizes, int n_in,
                              void* d_out, int out_size, void* d_ws, size_t ws_size,
                              hipStream_t stream){
  const float* x    = (const float*)d_in[0];
  const int*   idx  = (const int*)d_in[1];
  const float* wgt  = (const float*)d_in[2];
  const float* bias = (const float*)d_in[3];
  const int*   rate = (const int*)d_in[4];

  char* ws = (char*)d_ws;
  short* xT        = (short*)ws;                 // 8 MB token-major bf16
  short* wT2       = (short*)(ws + 8388608);     // 1 MB tiled weights [r][kc][n][k32]
  int*   segBucket = (int*)  (ws + 9437184);     // 64 KB (e-sorted per 256-token segment)
  int*   segCnt    = (int*)  (ws + 9502720);     // 2 KB  (64 segs x 8 experts)
  short* yT        = (short*)(ws + 10485760);    // 8 MB token-major bf16 (masked y)

  float* outx    = (float*)d_out;
  float* outm    = outx + (B_*C_*S_);
  float* idx_out = outx + 2*(B_*C_*S_);

  k_pre  <<<1216, 256, 0, stream>>>(x, xT, wgt, wT2, idx, rate, segCnt, segBucket, idx_out, outm);
  k_gemm <<<512,  256, 0, stream>>>(xT, wT2, bias, segCnt, segBucket, rate, yT);
  k_final<<<1024, 256, 0, stream>>>(yT, outx);
}